// Round 7
// baseline (270.121 us; speedup 1.0000x reference)
//
#include <hip/hip_runtime.h>
#include <hip/hip_bf16.h>
#include <stdint.h>
#include <stddef.h>

typedef __attribute__((ext_vector_type(8))) short bf16x8;       // 4-VGPR MFMA A/B frag (8 bf16)
typedef __attribute__((ext_vector_type(8))) unsigned short u16x8;
typedef __attribute__((ext_vector_type(4))) float f32x4;
typedef __attribute__((ext_vector_type(16))) float f32x16;      // 32x32 MFMA C/D frag

#define TT 1024

__device__ __forceinline__ unsigned short f2bf(float f){
  unsigned u = __builtin_bit_cast(unsigned, f);
  unsigned r = 0x7fffu + ((u >> 16) & 1u);
  return (unsigned short)((u + r) >> 16);
}
__device__ __forceinline__ float bf2f(unsigned short s){
  unsigned u = ((unsigned)s) << 16;
  return __builtin_bit_cast(float, u);
}
// async global->LDS, 16B per lane. LDS dest must be tid-linear (base + lane*16).
__device__ __forceinline__ void gload16(const unsigned short* g, unsigned short* l){
  __builtin_amdgcn_global_load_lds(
      (const __attribute__((address_space(1))) void*)g,
      (__attribute__((address_space(3))) void*)l, 16, 0, 0);
}

// ---------------- transpose + cast: in [R][C] fp32 -> out [C][R] bf16 ----------------
__global__ void transpose_cast_kernel(const float* __restrict__ in, unsigned short* __restrict__ out,
                                      int R, int C){
  __shared__ float tile[32][33];
  int c0 = blockIdx.x * 32, r0 = blockIdx.y * 32;
  for (int i = threadIdx.y; i < 32; i += 8)
    tile[i][threadIdx.x] = in[(size_t)(r0 + i) * C + c0 + threadIdx.x];
  __syncthreads();
  for (int i = threadIdx.y; i < 32; i += 8)
    out[(size_t)(c0 + i) * R + r0 + threadIdx.x] = f2bf(tile[threadIdx.x][i]);
}

// ---------------- RoPE cos/sin table ----------------
__global__ void rope_table_kernel(float* __restrict__ tab){
  int idx = blockIdx.x * 256 + threadIdx.x;   // 1024*32
  int pos = idx >> 5, i = idx & 31;
  float freq = powf(10000.0f, -(float)i / 32.0f);
  float ang = (float)pos * freq;
  tab[idx * 2]     = cosf(ang);
  tab[idx * 2 + 1] = sinf(ang);
}

// ---------------- fused: x cast->bf16 + router softmax/top4 gate (fp32) ----------------
__global__ __launch_bounds__(256) void prep_kernel(const float* __restrict__ x,
                                                   const float* __restrict__ wr,
                                                   unsigned short* __restrict__ x_bf,
                                                   float* __restrict__ gate){
  __shared__ float xc[8 * 256];
  __shared__ float red[8 * 8 * 32];
  const int tid = threadIdx.x;
  const int tok0 = blockIdx.x * 8;
  const int p = tid >> 5, h = tid & 31;
  float acc[8] = {0.f,0.f,0.f,0.f,0.f,0.f,0.f,0.f};

  for (int kb = 0; kb < 8; kb++){
    __syncthreads();
    {
      int tok = tid >> 5, e = (tid & 31) * 8;
      const float* xp = x + (size_t)(tok0 + tok) * 2048 + kb * 256 + e;
      float4 v0 = *(const float4*)xp, v1 = *(const float4*)(xp + 4);
      float vals[8] = {v0.x, v0.y, v0.z, v0.w, v1.x, v1.y, v1.z, v1.w};
      u16x8 ob;
      #pragma unroll
      for (int jj = 0; jj < 8; jj++) ob[jj] = f2bf(vals[jj]);
      *(u16x8*)(x_bf + (size_t)(tok0 + tok) * 2048 + kb * 256 + e) = ob;
      #pragma unroll
      for (int jj = 0; jj < 8; jj++) xc[tok * 256 + e + jj] = vals[jj];
    }
    __syncthreads();
    const float* wp = wr + (size_t)(kb * 256 + p * 32) * 32 + h;
    #pragma unroll 4
    for (int j = 0; j < 32; j++){
      float wv = wp[j * 32];
      #pragma unroll
      for (int tok = 0; tok < 8; tok++)
        acc[tok] += xc[tok * 256 + p * 32 + j] * wv;
    }
  }
  #pragma unroll
  for (int tok = 0; tok < 8; tok++) red[(p * 8 + tok) * 32 + h] = acc[tok];
  __syncthreads();
  {
    int lane = tid & 63;
    int tok = (tid >> 6) * 2 + (lane >> 5);
    int hh = lane & 31;
    float logit = 0.f;
    #pragma unroll
    for (int pp = 0; pp < 8; pp++) logit += red[(pp * 8 + tok) * 32 + hh];
    float m = logit;
    #pragma unroll
    for (int s = 16; s >= 1; s >>= 1) m = fmaxf(m, __shfl_xor(m, s));
    float e = __expf(logit - m);
    float sum = e;
    #pragma unroll
    for (int s = 16; s >= 1; s >>= 1) sum += __shfl_xor(sum, s);
    float prob = e / sum;
    float v = logit; int sel = 0;
    #pragma unroll
    for (int rr2 = 0; rr2 < 4; rr2++){
      float bv = v; int bi = hh;
      #pragma unroll
      for (int s = 16; s >= 1; s >>= 1){
        float ov = __shfl_xor(bv, s); int oi = __shfl_xor(bi, s);
        if (ov > bv || (ov == bv && oi < bi)) { bv = ov; bi = oi; }
      }
      if (hh == bi) { sel = 1; v = -3.4e38f; }
    }
    gate[(size_t)(tok0 + tok) * 32 + hh] = sel ? prob : 0.f;
  }
}

// ---------------- per-(b,h) active-token compaction (order-preserving) ----------------
__global__ void compact_kernel(const float* __restrict__ gate, int* __restrict__ idx,
                               int* __restrict__ counts){
  int bh = blockIdx.x;
  int b = bh >> 5, h = bh & 31;
  int lane = threadIdx.x;
  int base = 0;
  for (int c = 0; c < 16; c++){
    int t = c * 64 + lane;
    bool act = gate[(size_t)(b * TT + t) * 32 + h] != 0.f;
    unsigned long long mask = __ballot(act);
    int pos = base + __popcll(mask & ((1ull << lane) - 1ull));
    if (act) idx[bh * TT + pos] = t;
    base += __popcll(mask);
  }
  if (lane == 0) counts[bh] = base;
}

// ======== 32x32x16 GEMM: BM=256, BN=128, BK=64, 256 thr (4 waves 2Mx2N, 128x64/wave) ========
// 3-slot LDS ring (144KB dynamic), single barrier per K-tile, counted vmcnt(12),
// T2 xor-swizzle on 128B rows.  EPI=0: C fp32.  EPI=1: RoPE q/k -> qk, transposed V -> vt.
#define MFMA32(a, b, c) __builtin_amdgcn_mfma_f32_32x32x16_bf16((a), (b), (c), 0, 0, 0)

template<int EPI>
__global__ __launch_bounds__(256, 1) void gemm32(const unsigned short* __restrict__ A,
                                                 const unsigned short* __restrict__ Bt,
                                                 float* __restrict__ Cf,
                                                 unsigned short* __restrict__ qk,
                                                 unsigned short* __restrict__ vt,
                                                 const float* __restrict__ tab,
                                                 int N, int K, int nbm){
  extern __shared__ unsigned short smem[];   // 3 slots x 24576 ushorts (A 256x64 | B 128x64)

  // T1: bijective XCD swizzle (grid % 8 == 0); bn-major tile order (B panels L2-hot per XCD)
  const int nblk = gridDim.x;
  const int raw = blockIdx.x;
  const int tile = (raw & 7) * (nblk >> 3) + (raw >> 3);
  const int bn = tile / nbm, bm = tile % nbm;

  const int tid = threadIdx.x, lane = tid & 63, wid = tid >> 6;
  const int wrow = wid >> 1, wcol = wid & 1;
  const int l31 = lane & 31, hi = lane >> 5;
  const int X = (l31 & 7) << 4;              // row&7 == l31&7 for every frag row (offsets %32==0)

  // staging: linear LDS dest (tid*16 B), inverse-swizzled GLOBAL source (rule 21)
  const unsigned short* gA[8];
  const unsigned short* gB[4];
  #pragma unroll
  for (int p = 0; p < 8; p++){
    int L = tid * 16 + p * 4096;
    int r = L >> 7, c = (L & 127) ^ ((r & 7) << 4);
    gA[p] = A + (size_t)(bm * 256 + r) * K + (c >> 1);
  }
  #pragma unroll
  for (int p = 0; p < 4; p++){
    int L = tid * 16 + p * 4096;
    int r = L >> 7, c = (L & 127) ^ ((r & 7) << 4);
    gB[p] = Bt + (size_t)(bn * 128 + r) * K + (c >> 1);
  }

  auto stageA0 = [&](int tt){
    unsigned short* b = smem + (tt % 3) * 24576;
    size_t ko = (size_t)tt * 64;
    gload16(gA[0] + ko, b + tid * 8);
    gload16(gA[1] + ko, b + tid * 8 + 2048);
    gload16(gA[2] + ko, b + tid * 8 + 4096);
    gload16(gA[3] + ko, b + tid * 8 + 6144);
  };
  auto stageA1 = [&](int tt){
    unsigned short* b = smem + (tt % 3) * 24576;
    size_t ko = (size_t)tt * 64;
    gload16(gA[4] + ko, b + tid * 8 + 8192);
    gload16(gA[5] + ko, b + tid * 8 + 10240);
    gload16(gA[6] + ko, b + tid * 8 + 12288);
    gload16(gA[7] + ko, b + tid * 8 + 14336);
  };
  auto stageB = [&](int tt){
    unsigned short* b = smem + (tt % 3) * 24576 + 16384;
    size_t ko = (size_t)tt * 64;
    gload16(gB[0] + ko, b + tid * 8);
    gload16(gB[1] + ko, b + tid * 8 + 2048);
    gload16(gB[2] + ko, b + tid * 8 + 4096);
    gload16(gB[3] + ko, b + tid * 8 + 6144);
  };

  f32x16 acc[4][2];
  #pragma unroll
  for (int i = 0; i < 4; i++)
    #pragma unroll
    for (int j = 0; j < 2; j++) acc[i][j] = f32x16{0,0,0,0,0,0,0,0,0,0,0,0,0,0,0,0};

  const int NT = K >> 6;
  stageA0(0); stageA1(0); stageB(0);
  stageA0(1); stageA1(1); stageB(1);

  const int arow = (wrow * 128 + l31) * 64;      // ushort idx of A frag row base (i adds 32*64)
  const int brow = 16384 + (wcol * 64 + l31) * 64;

  for (int t = 0; t < NT; ++t){
    // tile t resident; tile t+1's 12 loads may stay in flight
    if (t < NT - 1) asm volatile("s_waitcnt vmcnt(12)" ::: "memory");
    else            asm volatile("s_waitcnt vmcnt(0)" ::: "memory");
    __builtin_amdgcn_s_barrier();
    __builtin_amdgcn_sched_barrier(0);
    const unsigned short* bs = smem + (t % 3) * 24576;
    const bool st = (t + 2 < NT);   // slot (t+2)%3 readers finished before this barrier
    #pragma unroll
    for (int ks = 0; ks < 4; ks++){
      const int kp = ((ks * 32 + hi * 16) ^ X) >> 1;
      bf16x8 a0 = *(const bf16x8*)(bs + arow +        kp);
      bf16x8 a1 = *(const bf16x8*)(bs + arow + 2048 + kp);
      bf16x8 a2 = *(const bf16x8*)(bs + arow + 4096 + kp);
      bf16x8 a3 = *(const bf16x8*)(bs + arow + 6144 + kp);
      bf16x8 b0 = *(const bf16x8*)(bs + brow +        kp);
      bf16x8 b1 = *(const bf16x8*)(bs + brow + 2048 + kp);
      if (st && ks == 0) stageA0(t + 2);
      if (st && ks == 1) stageA1(t + 2);
      if (st && ks == 2) stageB(t + 2);
      acc[0][0] = MFMA32(a0, b0, acc[0][0]); acc[0][1] = MFMA32(a0, b1, acc[0][1]);
      acc[1][0] = MFMA32(a1, b0, acc[1][0]); acc[1][1] = MFMA32(a1, b1, acc[1][1]);
      acc[2][0] = MFMA32(a2, b0, acc[2][0]); acc[2][1] = MFMA32(a2, b1, acc[2][1]);
      acc[3][0] = MFMA32(a3, b0, acc[3][0]); acc[3][1] = MFMA32(a3, b1, acc[3][1]);
    }
  }

  // ---- epilogue.  32x32 C/D: col = lane&31, row = (reg&3) + 8*(reg>>2) + 4*(lane>>5) ----
  if (EPI == 1){
    if (bn < 32){
      // q/k: RoPE pre-rounding (pairs = adjacent cols = lanes l, l^1, same rows)
      #pragma unroll
      for (int i = 0; i < 4; i++){
        #pragma unroll
        for (int j = 0; j < 2; j++){
          int col = bn * 128 + wcol * 64 + j * 32 + l31;
          int ii = (col & 63) >> 1;
          #pragma unroll
          for (int g = 0; g < 4; g++){
            #pragma unroll
            for (int rr = 0; rr < 4; rr++){
              int row = bm * 256 + wrow * 128 + i * 32 + g * 8 + hi * 4 + rr;
              int pos = row & (TT - 1);
              const float* tp = tab + ((size_t)pos * 32 + ii) * 2;
              float c = tp[0], s = tp[1];
              float val = acc[i][j][g * 4 + rr];
              float pv = __shfl_xor(val, 1);
              float res = (lane & 1) ? (pv * s + val * c) : (val * c - pv * s);
              qk[(size_t)row * 4096 + col] = f2bf(res);
            }
          }
        }
      }
    } else {
      // v: write transposed vt[(b*32+h)*64+d][t..t+3], 4 packed ushort4 per frag
      #pragma unroll
      for (int i = 0; i < 4; i++){
        #pragma unroll
        for (int j = 0; j < 2; j++){
          int vcol = bn * 128 + wcol * 64 + j * 32 + l31 - 4096;
          int hh = vcol >> 6, d = vcol & 63;
          int row0 = bm * 256 + wrow * 128 + i * 32 + hi * 4;
          int b = row0 >> 10, t0 = row0 & (TT - 1);
          #pragma unroll
          for (int g = 0; g < 4; g++){
            ushort4 pk;
            pk.x = f2bf(acc[i][j][g * 4 + 0]); pk.y = f2bf(acc[i][j][g * 4 + 1]);
            pk.z = f2bf(acc[i][j][g * 4 + 2]); pk.w = f2bf(acc[i][j][g * 4 + 3]);
            *(ushort4*)(vt + ((size_t)((b * 32 + hh) * 64 + d)) * TT + t0 + g * 8) = pk;
          }
        }
      }
    }
  } else {
    #pragma unroll
    for (int i = 0; i < 4; i++){
      #pragma unroll
      for (int j = 0; j < 2; j++){
        int col = bn * 128 + wcol * 64 + j * 32 + l31;
        #pragma unroll
        for (int g = 0; g < 4; g++){
          #pragma unroll
          for (int rr = 0; rr < 4; rr++){
            size_t row = (size_t)(bm * 256 + wrow * 128 + i * 32 + g * 8 + hi * 4 + rr);
            Cf[row * N + col] = acc[i][j][g * 4 + rr];
          }
        }
      }
    }
  }
}

// ---------------- sparse flash attention over gathered active q rows ----------------
#define MFMA_B16(a, b, c) __builtin_amdgcn_mfma_f32_16x16x32_bf16((a), (b), (c), 0, 0, 0)
__global__ __launch_bounds__(256) void attn_sparse_kernel(const unsigned short* __restrict__ qk,
                                                          const unsigned short* __restrict__ vt,
                                                          const float* __restrict__ gate,
                                                          const int* __restrict__ idx,
                                                          const int* __restrict__ counts,
                                                          unsigned short* __restrict__ attn_out){
  __shared__ unsigned short Ks[64 * 64];
  __shared__ unsigned short Vs[64 * 64];
  __shared__ unsigned short Ps[4][16 * 64];
  const int bh = blockIdx.x, qt = blockIdx.y;
  const int count = counts[bh];
  if (qt * 64 >= count) return;
  const int b = bh >> 5, h = bh & 31;
  const int tid = threadIdx.x, lane = tid & 63, w = tid >> 6;
  const int li = lane & 15, lg = lane >> 4;
  const int* myidx = idx + bh * TT + qt * 64;
  const int nvalid = min(64, count - qt * 64);
  const int qmax = myidx[nvalid - 1];

  int qi[4];
  #pragma unroll
  for (int r = 0; r < 4; r++){
    int s = w * 16 + lg * 4 + r;
    qi[r] = (s < nvalid) ? myidx[s] : -1;
  }
  int qrow = (w * 16 + li < nvalid) ? myidx[w * 16 + li] : 0;
  bf16x8 qf0, qf1;
  {
    const unsigned short* qp = qk + (size_t)(b * TT + qrow) * 4096 + h * 64;
    qf0 = *(const bf16x8*)(qp + lg * 8);
    qf1 = *(const bf16x8*)(qp + 32 + lg * 8);
  }
  f32x4 o[4];
  #pragma unroll
  for (int i = 0; i < 4; i++) o[i] = f32x4{0.f, 0.f, 0.f, 0.f};
  float m_run[4], l_run[4];
  #pragma unroll
  for (int r = 0; r < 4; r++){ m_run[r] = -1e30f; l_run[r] = 0.f; }

  const int nkt = (qmax >> 6) + 1;
  for (int kt = 0; kt < nkt; kt++){
    const int kb = kt * 64;
    #pragma unroll
    for (int s2 = 0; s2 < 2; s2++){
      int s = s2 * 256 + tid;
      int r = s >> 3, c = (s & 7) * 8;
      gload16(qk + (size_t)(b * TT + kb + r) * 4096 + 2048 + h * 64 + c, &Ks[s * 8]);
      gload16(vt + (size_t)(bh * 64 + r) * TT + kb + c, &Vs[s * 8]);
    }
    __syncthreads();

    f32x4 s4[4];
    #pragma unroll
    for (int ni = 0; ni < 4; ni++){
      bf16x8 k0 = *(const bf16x8*)(&Ks[(ni * 16 + li) * 64 + lg * 8]);
      bf16x8 k1 = *(const bf16x8*)(&Ks[(ni * 16 + li) * 64 + 32 + lg * 8]);
      f32x4 t = f32x4{0.f, 0.f, 0.f, 0.f};
      t = MFMA_B16(qf0, k0, t);
      t = MFMA_B16(qf1, k1, t);
      s4[ni] = t;
    }
    float mt[4];
    #pragma unroll
    for (int r = 0; r < 4; r++) mt[r] = -1e30f;
    #pragma unroll
    for (int ni = 0; ni < 4; ni++){
      int kidx = kb + ni * 16 + li;
      #pragma unroll
      for (int r = 0; r < 4; r++){
        float val = s4[ni][r] * 0.125f;
        val = (kidx <= qi[r]) ? val : -1e30f;
        s4[ni][r] = val;
        mt[r] = fmaxf(mt[r], val);
      }
    }
    #pragma unroll
    for (int r = 0; r < 4; r++){
      #pragma unroll
      for (int sh = 8; sh >= 1; sh >>= 1) mt[r] = fmaxf(mt[r], __shfl_xor(mt[r], sh));
      float mnew = fmaxf(m_run[r], mt[r]);
      float corr = __expf(m_run[r] - mnew);
      m_run[r] = mnew;
      l_run[r] *= corr;
      #pragma unroll
      for (int j = 0; j < 4; j++) o[j][r] *= corr;
    }
    float rs[4] = {0.f, 0.f, 0.f, 0.f};
    #pragma unroll
    for (int ni = 0; ni < 4; ni++)
      #pragma unroll
      for (int r = 0; r < 4; r++){
        float p = __expf(s4[ni][r] - m_run[r]);
        s4[ni][r] = p;
        rs[r] += p;
      }
    #pragma unroll
    for (int r = 0; r < 4; r++){
      #pragma unroll
      for (int sh = 8; sh >= 1; sh >>= 1) rs[r] += __shfl_xor(rs[r], sh);
      l_run[r] += rs[r];
    }
    #pragma unroll
    for (int ni = 0; ni < 4; ni++)
      #pragma unroll
      for (int r = 0; r < 4; r++)
        Ps[w][(lg * 4 + r) * 64 + ni * 16 + li] = f2bf(s4[ni][r]);
    #pragma unroll
    for (int ks = 0; ks < 2; ks++){
      bf16x8 pa = *(const bf16x8*)(&Ps[w][li * 64 + ks * 32 + lg * 8]);
      #pragma unroll
      for (int ni = 0; ni < 4; ni++){
        bf16x8 vb = *(const bf16x8*)(&Vs[(ni * 16 + li) * 64 + ks * 32 + lg * 8]);
        o[ni] = MFMA_B16(pa, vb, o[ni]);
      }
    }
    __syncthreads();
  }
  #pragma unroll
  for (int r = 0; r < 4; r++){
    if (qi[r] < 0) continue;
    float g = gate[(size_t)(b * TT + qi[r]) * 32 + h];
    float inv = g / l_run[r];
    #pragma unroll
    for (int ni = 0; ni < 4; ni++)
      attn_out[(size_t)(b * TT + qi[r]) * 2048 + h * 64 + ni * 16 + li] = f2bf(o[ni][r] * inv);
  }
}

extern "C" void kernel_launch(void* const* d_in, const int* in_sizes, int n_in,
                              void* d_out, int out_size, void* d_ws, size_t ws_size,
                              hipStream_t stream){
  const float* x        = (const float*)d_in[0];
  const float* w_router = (const float*)d_in[1];
  const float* w_qkv    = (const float*)d_in[2];
  const float* w_out    = (const float*)d_in[3];
  float* out = (float*)d_out;
  char* ws = (char*)d_ws;

  unsigned short* qk    = (unsigned short*)(ws);                        // 33554432 B [4096][4096]
  unsigned short* vt    = (unsigned short*)(ws + 33554432);             // 16777216 B
  unsigned short* x_bf  = (unsigned short*)(ws + 50331648);             // 16777216 B
  unsigned short* wqkvT = (unsigned short*)(ws + 67108864);             // 25165824 B
  unsigned short* woutT = (unsigned short*)(ws + 92274688);             // 8388608 B
  float* gate           = (float*)(ws + 100663296);                     // 524288 B
  float* tab            = (float*)(ws + 101187584);                     // 262144 B
  unsigned short* attn  = x_bf;                      // reuse after qkv GEMM
  int* idx              = (int*)(ws + 67108864);     // reuse wqkvT region after qkv GEMM
  int* counts           = (int*)(ws + 67633152);

  constexpr int GEMM_LDS = 147456;  // 3 slots x 48 KB
  (void)hipFuncSetAttribute(reinterpret_cast<const void*>(&gemm32<1>),
                            hipFuncAttributeMaxDynamicSharedMemorySize, GEMM_LDS);
  (void)hipFuncSetAttribute(reinterpret_cast<const void*>(&gemm32<0>),
                            hipFuncAttributeMaxDynamicSharedMemorySize, GEMM_LDS);

  hipLaunchKernelGGL(transpose_cast_kernel, dim3(192, 64), dim3(32, 8), 0, stream, w_qkv, wqkvT, 2048, 6144);
  hipLaunchKernelGGL(transpose_cast_kernel, dim3(64, 64), dim3(32, 8), 0, stream, w_out, woutT, 2048, 2048);
  hipLaunchKernelGGL(rope_table_kernel, dim3(128), dim3(256), 0, stream, tab);
  hipLaunchKernelGGL(prep_kernel, dim3(512), dim3(256), 0, stream, x, w_router, x_bf, gate);
  hipLaunchKernelGGL((gemm32<1>), dim3(768), dim3(256), GEMM_LDS, stream,
                     x_bf, wqkvT, (float*)nullptr, qk, vt, tab, 6144, 2048, 16);
  hipLaunchKernelGGL(compact_kernel, dim3(128), dim3(64), 0, stream, gate, idx, counts);
  (void)hipMemsetAsync(attn, 0, (size_t)4096 * 2048 * 2, stream);
  hipLaunchKernelGGL(attn_sparse_kernel, dim3(128, 16), dim3(256), 0, stream, qk, vt, gate, idx, counts, attn);
  hipLaunchKernelGGL((gemm32<0>), dim3(256), dim3(256), GEMM_LDS, stream,
                     attn, woutT, out, (unsigned short*)nullptr, (unsigned short*)nullptr,
                     (const float*)nullptr, 2048, 2048, 16);
}

// Round 8
// 263.522 us; speedup vs baseline: 1.0250x; 1.0250x over previous
//
#include <hip/hip_runtime.h>
#include <hip/hip_bf16.h>
#include <stdint.h>
#include <stddef.h>

typedef __attribute__((ext_vector_type(8))) short bf16x8;       // 4-VGPR MFMA A/B frag (8 bf16)
typedef __attribute__((ext_vector_type(8))) unsigned short u16x8;
typedef __attribute__((ext_vector_type(4))) float f32x4;
typedef __attribute__((ext_vector_type(16))) float f32x16;      // 32x32 MFMA C/D frag

#define TT 1024

__device__ __forceinline__ unsigned short f2bf(float f){
  unsigned u = __builtin_bit_cast(unsigned, f);
  unsigned r = 0x7fffu + ((u >> 16) & 1u);
  return (unsigned short)((u + r) >> 16);
}
__device__ __forceinline__ float bf2f(unsigned short s){
  unsigned u = ((unsigned)s) << 16;
  return __builtin_bit_cast(float, u);
}
// async global->LDS, 16B per lane. LDS dest must be tid-linear (base + lane*16).
__device__ __forceinline__ void gload16(const unsigned short* g, unsigned short* l){
  __builtin_amdgcn_global_load_lds(
      (const __attribute__((address_space(1))) void*)g,
      (__attribute__((address_space(3))) void*)l, 16, 0, 0);
}

#define MFMA32(a, b, c) __builtin_amdgcn_mfma_f32_32x32x16_bf16((a), (b), (c), 0, 0, 0)
#define MFMA_B16(a, b, c) __builtin_amdgcn_mfma_f32_16x16x32_bf16((a), (b), (c), 0, 0, 0)

// ---------------- transpose + cast: in [R][C] fp32 -> out [C][R] bf16 ----------------
__global__ void transpose_cast_kernel(const float* __restrict__ in, unsigned short* __restrict__ out,
                                      int R, int C){
  __shared__ float tile[32][33];
  int c0 = blockIdx.x * 32, r0 = blockIdx.y * 32;
  for (int i = threadIdx.y; i < 32; i += 8)
    tile[i][threadIdx.x] = in[(size_t)(r0 + i) * C + c0 + threadIdx.x];
  __syncthreads();
  for (int i = threadIdx.y; i < 32; i += 8)
    out[(size_t)(c0 + i) * R + r0 + threadIdx.x] = f2bf(tile[threadIdx.x][i]);
}

// ---------------- RoPE cos/sin table ----------------
__global__ void rope_table_kernel(float* __restrict__ tab){
  int idx = blockIdx.x * 256 + threadIdx.x;   // 1024*32
  int pos = idx >> 5, i = idx & 31;
  float freq = powf(10000.0f, -(float)i / 32.0f);
  float ang = (float)pos * freq;
  tab[idx * 2]     = cosf(ang);
  tab[idx * 2 + 1] = sinf(ang);
}

// ------- fused: x cast->bf16 + router softmax/top4 gate (fp32) + active-head list -------
__global__ __launch_bounds__(256) void prep_kernel(const float* __restrict__ x,
                                                   const float* __restrict__ wr,
                                                   unsigned short* __restrict__ x_bf,
                                                   float* __restrict__ gate,
                                                   unsigned char* __restrict__ heads4){
  __shared__ float xc[8 * 256];
  __shared__ float red[8 * 8 * 32];
  const int tid = threadIdx.x;
  const int tok0 = blockIdx.x * 8;
  const int p = tid >> 5, h = tid & 31;
  float acc[8] = {0.f,0.f,0.f,0.f,0.f,0.f,0.f,0.f};

  for (int kb = 0; kb < 8; kb++){
    __syncthreads();
    {
      int tok = tid >> 5, e = (tid & 31) * 8;
      const float* xp = x + (size_t)(tok0 + tok) * 2048 + kb * 256 + e;
      float4 v0 = *(const float4*)xp, v1 = *(const float4*)(xp + 4);
      float vals[8] = {v0.x, v0.y, v0.z, v0.w, v1.x, v1.y, v1.z, v1.w};
      u16x8 ob;
      #pragma unroll
      for (int jj = 0; jj < 8; jj++) ob[jj] = f2bf(vals[jj]);
      *(u16x8*)(x_bf + (size_t)(tok0 + tok) * 2048 + kb * 256 + e) = ob;
      #pragma unroll
      for (int jj = 0; jj < 8; jj++) xc[tok * 256 + e + jj] = vals[jj];
    }
    __syncthreads();
    const float* wp = wr + (size_t)(kb * 256 + p * 32) * 32 + h;
    #pragma unroll 4
    for (int j = 0; j < 32; j++){
      float wv = wp[j * 32];
      #pragma unroll
      for (int tok = 0; tok < 8; tok++)
        acc[tok] += xc[tok * 256 + p * 32 + j] * wv;
    }
  }
  #pragma unroll
  for (int tok = 0; tok < 8; tok++) red[(p * 8 + tok) * 32 + h] = acc[tok];
  __syncthreads();
  {
    int lane = tid & 63;
    int tok = (tid >> 6) * 2 + (lane >> 5);
    int hh = lane & 31;
    float logit = 0.f;
    #pragma unroll
    for (int pp = 0; pp < 8; pp++) logit += red[(pp * 8 + tok) * 32 + hh];
    float m = logit;
    #pragma unroll
    for (int s = 16; s >= 1; s >>= 1) m = fmaxf(m, __shfl_xor(m, s));
    float e = __expf(logit - m);
    float sum = e;
    #pragma unroll
    for (int s = 16; s >= 1; s >>= 1) sum += __shfl_xor(sum, s);
    float prob = e / sum;
    float v = logit; int sel = 0;
    #pragma unroll
    for (int rr2 = 0; rr2 < 4; rr2++){
      float bv = v; int bi = hh;
      #pragma unroll
      for (int s = 16; s >= 1; s >>= 1){
        float ov = __shfl_xor(bv, s); int oi = __shfl_xor(bi, s);
        if (ov > bv || (ov == bv && oi < bi)) { bv = ov; bi = oi; }
      }
      if (hh == bi) { sel = 1; v = -3.4e38f; }
    }
    gate[(size_t)(tok0 + tok) * 32 + hh] = sel ? prob : 0.f;
    // rank of this head among the token's 4 active heads (ascending head id)
    unsigned long long bal = __ballot(sel != 0);
    unsigned selmask = (unsigned)(bal >> ((lane >> 5) * 32));
    if (sel){
      int r = __popc(selmask & ((1u << hh) - 1u));
      heads4[(size_t)(tok0 + tok) * 4 + r] = (unsigned char)hh;
    }
  }
}

// ------- per-(b,h) active-token compaction; entry = tok | (rank<<10), order-preserving -------
__global__ void compact_kernel(const unsigned char* __restrict__ heads4,
                               unsigned short* __restrict__ idx, int* __restrict__ counts){
  int bh = blockIdx.x;
  int b = bh >> 5, h = bh & 31;
  int lane = threadIdx.x;
  int base = 0;
  for (int c = 0; c < 16; c++){
    int t = c * 64 + lane;
    unsigned u = ((const unsigned*)heads4)[b * 1024 + t];
    int r = -1;
    if (((u      ) & 255) == (unsigned)h) r = 0;
    else if (((u >>  8) & 255) == (unsigned)h) r = 1;
    else if (((u >> 16) & 255) == (unsigned)h) r = 2;
    else if (((u >> 24) & 255) == (unsigned)h) r = 3;
    bool act = (r >= 0);
    unsigned long long mask = __ballot(act);
    int pos = base + __popcll(mask & ((1ull << lane) - 1ull));
    if (act) idx[bh * 1024 + pos] = (unsigned short)(t | (r << 10));
    base += __popcll(mask);
  }
  if (lane == 0) counts[bh] = base;
}

// ---------------- sparse Q GEMM + RoPE: per (bh, qt), 4 waves K-split ----------------
__global__ __launch_bounds__(256) void qgemm_kernel(const unsigned short* __restrict__ x_bf,
                                                    const unsigned short* __restrict__ wqkvT,
                                                    const unsigned short* __restrict__ idx,
                                                    const int* __restrict__ counts,
                                                    const float* __restrict__ tab,
                                                    unsigned short* __restrict__ qact){
  __shared__ float red[4][64][64];   // 64 KB
  const int bh = blockIdx.x, qt = blockIdx.y;
  const int count = counts[bh];
  if (qt * 64 >= count) return;
  const int b = bh >> 5, h = bh & 31;
  const int tid = threadIdx.x, lane = tid & 63, w = tid >> 6;
  const int li = lane & 15, lg = lane >> 4;
  const int nvalid = min(64, count - qt * 64);
  const unsigned short* myidx = idx + bh * 1024 + qt * 64;

  int atok[4];
  #pragma unroll
  for (int ai = 0; ai < 4; ai++){
    int s = ai * 16 + li;
    atok[ai] = (s < nvalid) ? (myidx[s] & 1023) : 0;
  }
  const unsigned short* Bbase = wqkvT + (size_t)(h * 64) * 2048;

  f32x4 acc[4][4];
  #pragma unroll
  for (int i = 0; i < 4; i++)
    #pragma unroll
    for (int j = 0; j < 4; j++) acc[i][j] = f32x4{0.f, 0.f, 0.f, 0.f};

  const int k0w = w * 512;
  #pragma unroll 2
  for (int ks = 0; ks < 16; ks++){
    int k0 = k0w + ks * 32 + lg * 8;
    bf16x8 af[4], bw[4];
    #pragma unroll
    for (int ai = 0; ai < 4; ai++)
      af[ai] = *(const bf16x8*)(x_bf + (size_t)(b * 1024 + atok[ai]) * 2048 + k0);
    #pragma unroll
    for (int ni = 0; ni < 4; ni++)
      bw[ni] = *(const bf16x8*)(Bbase + (size_t)(ni * 16 + li) * 2048 + k0);
    #pragma unroll
    for (int ai = 0; ai < 4; ai++)
      #pragma unroll
      for (int ni = 0; ni < 4; ni++)
        acc[ai][ni] = MFMA_B16(af[ai], bw[ni], acc[ai][ni]);
  }
  #pragma unroll
  for (int ai = 0; ai < 4; ai++)
    #pragma unroll
    for (int ni = 0; ni < 4; ni++)
      #pragma unroll
      for (int rr = 0; rr < 4; rr++)
        red[w][ai * 16 + lg * 4 + rr][ni * 16 + li] = acc[ai][ni][rr];
  __syncthreads();

  int q = tid >> 2, dbase = (tid & 3) * 16;
  if (q < nvalid){
    int e = myidx[q];
    int tok = e & 1023, r = e >> 10;
    unsigned short* op = qact + ((size_t)((b << 10) + tok) * 4 + r) * 64;
    const float* tp = tab + ((size_t)tok * 32 + (dbase >> 1)) * 2;
    #pragma unroll
    for (int p = 0; p < 8; p++){
      int d0 = dbase + 2 * p;
      float v0 = red[0][q][d0] + red[1][q][d0] + red[2][q][d0] + red[3][q][d0];
      float v1 = red[0][q][d0 + 1] + red[1][q][d0 + 1] + red[2][q][d0 + 1] + red[3][q][d0 + 1];
      float c = tp[2 * p], s = tp[2 * p + 1];
      op[d0]     = f2bf(v0 * c - v1 * s);
      op[d0 + 1] = f2bf(v0 * s + v1 * c);
    }
  }
}

// ======== 32x32x16 KV GEMM: BM=256, BN=128, BK=64, 256 thr (4 waves 2Mx2N) ========
// Bt = wqkvT rows 2048..6143.  bn<16: RoPE'd K -> kbuf[4096][2048]; bn>=16: V^T -> vt.
// EPI=0 variant: plain fp32 C (out-projection GEMM).
template<int EPI>
__global__ __launch_bounds__(256, 1) void gemm32(const unsigned short* __restrict__ A,
                                                 const unsigned short* __restrict__ Bt,
                                                 float* __restrict__ Cf,
                                                 unsigned short* __restrict__ kbuf,
                                                 unsigned short* __restrict__ vt,
                                                 const float* __restrict__ tab,
                                                 int N, int K, int nbm){
  extern __shared__ unsigned short smem[];   // 3 slots x 24576 ushorts (A 256x64 | B 128x64)
  const int nblk = gridDim.x;
  const int raw = blockIdx.x;
  const int tile = (raw & 7) * (nblk >> 3) + (raw >> 3);
  const int bn = tile / nbm, bm = tile % nbm;

  const int tid = threadIdx.x, lane = tid & 63, wid = tid >> 6;
  const int wrow = wid >> 1, wcol = wid & 1;
  const int l31 = lane & 31, hi = lane >> 5;
  const int X = (l31 & 7) << 4;

  const unsigned short* gA[8];
  const unsigned short* gB[4];
  #pragma unroll
  for (int p = 0; p < 8; p++){
    int L = tid * 16 + p * 4096;
    int r = L >> 7, c = (L & 127) ^ ((r & 7) << 4);
    gA[p] = A + (size_t)(bm * 256 + r) * K + (c >> 1);
  }
  #pragma unroll
  for (int p = 0; p < 4; p++){
    int L = tid * 16 + p * 4096;
    int r = L >> 7, c = (L & 127) ^ ((r & 7) << 4);
    gB[p] = Bt + (size_t)(bn * 128 + r) * K + (c >> 1);
  }

  auto stageA0 = [&](int tt){
    unsigned short* b = smem + (tt % 3) * 24576;
    size_t ko = (size_t)tt * 64;
    gload16(gA[0] + ko, b + tid * 8);
    gload16(gA[1] + ko, b + tid * 8 + 2048);
    gload16(gA[2] + ko, b + tid * 8 + 4096);
    gload16(gA[3] + ko, b + tid * 8 + 6144);
  };
  auto stageA1 = [&](int tt){
    unsigned short* b = smem + (tt % 3) * 24576;
    size_t ko = (size_t)tt * 64;
    gload16(gA[4] + ko, b + tid * 8 + 8192);
    gload16(gA[5] + ko, b + tid * 8 + 10240);
    gload16(gA[6] + ko, b + tid * 8 + 12288);
    gload16(gA[7] + ko, b + tid * 8 + 14336);
  };
  auto stageB = [&](int tt){
    unsigned short* b = smem + (tt % 3) * 24576 + 16384;
    size_t ko = (size_t)tt * 64;
    gload16(gB[0] + ko, b + tid * 8);
    gload16(gB[1] + ko, b + tid * 8 + 2048);
    gload16(gB[2] + ko, b + tid * 8 + 4096);
    gload16(gB[3] + ko, b + tid * 8 + 6144);
  };

  f32x16 acc[4][2];
  #pragma unroll
  for (int i = 0; i < 4; i++)
    #pragma unroll
    for (int j = 0; j < 2; j++) acc[i][j] = f32x16{0,0,0,0,0,0,0,0,0,0,0,0,0,0,0,0};

  const int NT = K >> 6;
  stageA0(0); stageA1(0); stageB(0);
  stageA0(1); stageA1(1); stageB(1);

  const int arow = (wrow * 128 + l31) * 64;
  const int brow = 16384 + (wcol * 64 + l31) * 64;

  for (int t = 0; t < NT; ++t){
    if (t < NT - 1) asm volatile("s_waitcnt vmcnt(12)" ::: "memory");
    else            asm volatile("s_waitcnt vmcnt(0)" ::: "memory");
    __builtin_amdgcn_s_barrier();
    __builtin_amdgcn_sched_barrier(0);
    const unsigned short* bs = smem + (t % 3) * 24576;
    const bool st = (t + 2 < NT);
    #pragma unroll
    for (int ks = 0; ks < 4; ks++){
      const int kp = ((ks * 32 + hi * 16) ^ X) >> 1;
      bf16x8 a0 = *(const bf16x8*)(bs + arow +        kp);
      bf16x8 a1 = *(const bf16x8*)(bs + arow + 2048 + kp);
      bf16x8 a2 = *(const bf16x8*)(bs + arow + 4096 + kp);
      bf16x8 a3 = *(const bf16x8*)(bs + arow + 6144 + kp);
      bf16x8 b0 = *(const bf16x8*)(bs + brow +        kp);
      bf16x8 b1 = *(const bf16x8*)(bs + brow + 2048 + kp);
      if (st && ks == 0) stageA0(t + 2);
      if (st && ks == 1) stageA1(t + 2);
      if (st && ks == 2) stageB(t + 2);
      acc[0][0] = MFMA32(a0, b0, acc[0][0]); acc[0][1] = MFMA32(a0, b1, acc[0][1]);
      acc[1][0] = MFMA32(a1, b0, acc[1][0]); acc[1][1] = MFMA32(a1, b1, acc[1][1]);
      acc[2][0] = MFMA32(a2, b0, acc[2][0]); acc[2][1] = MFMA32(a2, b1, acc[2][1]);
      acc[3][0] = MFMA32(a3, b0, acc[3][0]); acc[3][1] = MFMA32(a3, b1, acc[3][1]);
    }
  }

  // 32x32 C/D: col = lane&31, row = (reg&3) + 8*(reg>>2) + 4*(lane>>5)
  if (EPI == 1){
    if (bn < 16){
      // K section: RoPE pre-rounding, write kbuf[row][col], col in [0,2048)
      #pragma unroll
      for (int i = 0; i < 4; i++){
        #pragma unroll
        for (int j = 0; j < 2; j++){
          int col = bn * 128 + wcol * 64 + j * 32 + l31;
          int ii = (col & 63) >> 1;
          #pragma unroll
          for (int g = 0; g < 4; g++){
            #pragma unroll
            for (int rr = 0; rr < 4; rr++){
              int row = bm * 256 + wrow * 128 + i * 32 + g * 8 + hi * 4 + rr;
              int pos = row & (TT - 1);
              const float* tp = tab + ((size_t)pos * 32 + ii) * 2;
              float c = tp[0], s = tp[1];
              float val = acc[i][j][g * 4 + rr];
              float pv = __shfl_xor(val, 1);
              float res = (lane & 1) ? (pv * s + val * c) : (val * c - pv * s);
              kbuf[(size_t)row * 2048 + col] = f2bf(res);
            }
          }
        }
      }
    } else {
      // V section: write transposed vt[(b*32+h)*64+d][t..t+3]
      #pragma unroll
      for (int i = 0; i < 4; i++){
        #pragma unroll
        for (int j = 0; j < 2; j++){
          int vcol = bn * 128 + wcol * 64 + j * 32 + l31 - 2048;
          int hh = vcol >> 6, d = vcol & 63;
          int row0 = bm * 256 + wrow * 128 + i * 32 + hi * 4;
          int b = row0 >> 10, t0 = row0 & (TT - 1);
          #pragma unroll
          for (int g = 0; g < 4; g++){
            ushort4 pk;
            pk.x = f2bf(acc[i][j][g * 4 + 0]); pk.y = f2bf(acc[i][j][g * 4 + 1]);
            pk.z = f2bf(acc[i][j][g * 4 + 2]); pk.w = f2bf(acc[i][j][g * 4 + 3]);
            *(ushort4*)(vt + ((size_t)((b * 32 + hh) * 64 + d)) * TT + t0 + g * 8) = pk;
          }
        }
      }
    }
  } else {
    #pragma unroll
    for (int i = 0; i < 4; i++){
      #pragma unroll
      for (int j = 0; j < 2; j++){
        int col = bn * 128 + wcol * 64 + j * 32 + l31;
        #pragma unroll
        for (int g = 0; g < 4; g++){
          #pragma unroll
          for (int rr = 0; rr < 4; rr++){
            size_t row = (size_t)(bm * 256 + wrow * 128 + i * 32 + g * 8 + hi * 4 + rr);
            Cf[row * N + col] = acc[i][j][g * 4 + rr];
          }
        }
      }
    }
  }
}

// ---------------- sparse flash attention over gathered active q rows ----------------
__global__ __launch_bounds__(256) void attn_sparse_kernel(const unsigned short* __restrict__ qact,
                                                          const unsigned short* __restrict__ kbuf,
                                                          const unsigned short* __restrict__ vt,
                                                          const float* __restrict__ gate,
                                                          const unsigned short* __restrict__ idx,
                                                          const int* __restrict__ counts,
                                                          unsigned short* __restrict__ attn_out){
  __shared__ unsigned short Ks[64 * 64];
  __shared__ unsigned short Vs[64 * 64];
  __shared__ unsigned short Ps[4][16 * 64];
  const int bh = blockIdx.x, qt = blockIdx.y;
  const int count = counts[bh];
  if (qt * 64 >= count) return;
  const int b = bh >> 5, h = bh & 31;
  const int tid = threadIdx.x, lane = tid & 63, w = tid >> 6;
  const int li = lane & 15, lg = lane >> 4;
  const unsigned short* myidx = idx + bh * 1024 + qt * 64;
  const int nvalid = min(64, count - qt * 64);
  const int qmax = myidx[nvalid - 1] & 1023;

  int qi[4];
  #pragma unroll
  for (int r = 0; r < 4; r++){
    int s = w * 16 + lg * 4 + r;
    qi[r] = (s < nvalid) ? (myidx[s] & 1023) : -1;
  }
  bf16x8 qf0, qf1;
  {
    int s = w * 16 + li;
    int e2 = (s < nvalid) ? myidx[s] : 0;
    const unsigned short* qp = qact + ((size_t)((b << 10) + (e2 & 1023)) * 4 + (e2 >> 10)) * 64;
    qf0 = *(const bf16x8*)(qp + lg * 8);
    qf1 = *(const bf16x8*)(qp + 32 + lg * 8);
  }
  f32x4 o[4];
  #pragma unroll
  for (int i = 0; i < 4; i++) o[i] = f32x4{0.f, 0.f, 0.f, 0.f};
  float m_run[4], l_run[4];
  #pragma unroll
  for (int r = 0; r < 4; r++){ m_run[r] = -1e30f; l_run[r] = 0.f; }

  const int nkt = (qmax >> 6) + 1;
  for (int kt = 0; kt < nkt; kt++){
    const int kb = kt * 64;
    #pragma unroll
    for (int s2 = 0; s2 < 2; s2++){
      int s = s2 * 256 + tid;
      int r = s >> 3, c = (s & 7) * 8;
      gload16(kbuf + (size_t)(b * TT + kb + r) * 2048 + h * 64 + c, &Ks[s * 8]);
      gload16(vt + (size_t)(bh * 64 + r) * TT + kb + c, &Vs[s * 8]);
    }
    __syncthreads();

    f32x4 s4[4];
    #pragma unroll
    for (int ni = 0; ni < 4; ni++){
      bf16x8 k0 = *(const bf16x8*)(&Ks[(ni * 16 + li) * 64 + lg * 8]);
      bf16x8 k1 = *(const bf16x8*)(&Ks[(ni * 16 + li) * 64 + 32 + lg * 8]);
      f32x4 t = f32x4{0.f, 0.f, 0.f, 0.f};
      t = MFMA_B16(qf0, k0, t);
      t = MFMA_B16(qf1, k1, t);
      s4[ni] = t;
    }
    float mt[4];
    #pragma unroll
    for (int r = 0; r < 4; r++) mt[r] = -1e30f;
    #pragma unroll
    for (int ni = 0; ni < 4; ni++){
      int kidx = kb + ni * 16 + li;
      #pragma unroll
      for (int r = 0; r < 4; r++){
        float val = s4[ni][r] * 0.125f;
        val = (kidx <= qi[r]) ? val : -1e30f;
        s4[ni][r] = val;
        mt[r] = fmaxf(mt[r], val);
      }
    }
    #pragma unroll
    for (int r = 0; r < 4; r++){
      #pragma unroll
      for (int sh = 8; sh >= 1; sh >>= 1) mt[r] = fmaxf(mt[r], __shfl_xor(mt[r], sh));
      float mnew = fmaxf(m_run[r], mt[r]);
      float corr = __expf(m_run[r] - mnew);
      m_run[r] = mnew;
      l_run[r] *= corr;
      #pragma unroll
      for (int j = 0; j < 4; j++) o[j][r] *= corr;
    }
    float rs[4] = {0.f, 0.f, 0.f, 0.f};
    #pragma unroll
    for (int ni = 0; ni < 4; ni++)
      #pragma unroll
      for (int r = 0; r < 4; r++){
        float p = __expf(s4[ni][r] - m_run[r]);
        s4[ni][r] = p;
        rs[r] += p;
      }
    #pragma unroll
    for (int r = 0; r < 4; r++){
      #pragma unroll
      for (int sh = 8; sh >= 1; sh >>= 1) rs[r] += __shfl_xor(rs[r], sh);
      l_run[r] += rs[r];
    }
    #pragma unroll
    for (int ni = 0; ni < 4; ni++)
      #pragma unroll
      for (int r = 0; r < 4; r++)
        Ps[w][(lg * 4 + r) * 64 + ni * 16 + li] = f2bf(s4[ni][r]);
    #pragma unroll
    for (int ks = 0; ks < 2; ks++){
      bf16x8 pa = *(const bf16x8*)(&Ps[w][li * 64 + ks * 32 + lg * 8]);
      #pragma unroll
      for (int ni = 0; ni < 4; ni++){
        bf16x8 vb = *(const bf16x8*)(&Vs[(ni * 16 + li) * 64 + ks * 32 + lg * 8]);
        o[ni] = MFMA_B16(pa, vb, o[ni]);
      }
    }
    __syncthreads();
  }
  #pragma unroll
  for (int r = 0; r < 4; r++){
    if (qi[r] < 0) continue;
    float g = gate[(size_t)(b * TT + qi[r]) * 32 + h];
    float inv = g / l_run[r];
    #pragma unroll
    for (int ni = 0; ni < 4; ni++)
      attn_out[(size_t)(b * TT + qi[r]) * 2048 + h * 64 + ni * 16 + li] = f2bf(o[ni][r] * inv);
  }
}

extern "C" void kernel_launch(void* const* d_in, const int* in_sizes, int n_in,
                              void* d_out, int out_size, void* d_ws, size_t ws_size,
                              hipStream_t stream){
  const float* x        = (const float*)d_in[0];
  const float* w_router = (const float*)d_in[1];
  const float* w_qkv    = (const float*)d_in[2];
  const float* w_out    = (const float*)d_in[3];
  float* out = (float*)d_out;
  char* ws = (char*)d_ws;

  unsigned short* kbuf   = (unsigned short*)(ws);                       // 16,777,216 [4096][2048]
  unsigned short* vt     = (unsigned short*)(ws + 16777216);            // 16,777,216
  unsigned short* qact   = (unsigned short*)(ws + 33554432);            //  4,194,304 [4096tok][4r][64]
  unsigned short* idx    = (unsigned short*)(ws + 37748736);            //    262,144 [128][1024]
  int* counts            = (int*)(ws + 38010880);                       //        512
  unsigned char* heads4  = (unsigned char*)(ws + 38011392);             //     16,384
  unsigned short* x_bf   = (unsigned short*)(ws + 50331648);            // 16,777,216
  unsigned short* wqkvT  = (unsigned short*)(ws + 67108864);            // 25,165,824
  unsigned short* woutT  = (unsigned short*)(ws + 92274688);            //  8,388,608
  float* gate            = (float*)(ws + 100663296);                    //    524,288
  float* tab             = (float*)(ws + 101187584);                    //    262,144 (peak 101,449,728)
  unsigned short* attn   = x_bf;                    // reuse after both GEMMs read x_bf

  constexpr int GEMM_LDS = 147456;  // 3 slots x 48 KB
  (void)hipFuncSetAttribute(reinterpret_cast<const void*>(&gemm32<1>),
                            hipFuncAttributeMaxDynamicSharedMemorySize, GEMM_LDS);
  (void)hipFuncSetAttribute(reinterpret_cast<const void*>(&gemm32<0>),
                            hipFuncAttributeMaxDynamicSharedMemorySize, GEMM_LDS);

  hipLaunchKernelGGL(transpose_cast_kernel, dim3(192, 64), dim3(32, 8), 0, stream, w_qkv, wqkvT, 2048, 6144);
  hipLaunchKernelGGL(transpose_cast_kernel, dim3(64, 64), dim3(32, 8), 0, stream, w_out, woutT, 2048, 2048);
  hipLaunchKernelGGL(rope_table_kernel, dim3(128), dim3(256), 0, stream, tab);
  hipLaunchKernelGGL(prep_kernel, dim3(512), dim3(256), 0, stream, x, w_router, x_bf, gate, heads4);
  hipLaunchKernelGGL(compact_kernel, dim3(128), dim3(64), 0, stream, heads4, idx, counts);
  // KV GEMM: N=4096 (K,V weight rows 2048..6143), grid 32x16 = 512 = 2 full CU rounds
  hipLaunchKernelGGL((gemm32<1>), dim3(512), dim3(256), GEMM_LDS, stream,
                     x_bf, wqkvT + (size_t)2048 * 2048, (float*)nullptr, kbuf, vt, tab, 4096, 2048, 16);
  // sparse Q GEMM over active rows only (1/8 of Q work)
  hipLaunchKernelGGL(qgemm_kernel, dim3(128, 16), dim3(256), 0, stream,
                     x_bf, wqkvT, idx, counts, tab, qact);
  (void)hipMemsetAsync(attn, 0, (size_t)4096 * 2048 * 2, stream);
  hipLaunchKernelGGL(attn_sparse_kernel, dim3(128, 16), dim3(256), 0, stream,
                     qact, kbuf, vt, gate, idx, counts, attn);
  hipLaunchKernelGGL((gemm32<0>), dim3(256), dim3(256), GEMM_LDS, stream,
                     attn, woutT, out, (unsigned short*)nullptr, (unsigned short*)nullptr,
                     (const float*)nullptr, 2048, 2048, 16);
}